// Round 4
// baseline (62.092 us; speedup 1.0000x reference)
//
#include <hip/hip_runtime.h>
#include <hip/hip_bf16.h>

typedef __bf16 bf16_t;
typedef bf16_t bf16x8 __attribute__((ext_vector_type(8)));
typedef float f32x4 __attribute__((ext_vector_type(4)));

#define KD 768
#define BDIM 4096
#define NT 12        // K-tiles of BK=64
#define BM 256
#define BN 128

#define GLOAD_LDS16(gptr, lptr)                                             \
    __builtin_amdgcn_global_load_lds(                                       \
        (const __attribute__((address_space(1))) unsigned int*)(gptr),      \
        (__attribute__((address_space(3))) unsigned int*)(lptr), 16, 0, 0)

#define BAR()   __builtin_amdgcn_s_barrier()
#define LGKM0() asm volatile("s_waitcnt lgkmcnt(0)" ::: "memory")

// ---------------- Kernel 1: row-normalize fp32 -> bf16 ----------------
__global__ __launch_bounds__(256) void normalize_rows(
    const float* __restrict__ x, __hip_bfloat16* __restrict__ xn)
{
    const int row = blockIdx.x;
    const int t = threadIdx.x;
    const float* xr = x + (long)row * KD;

    float v[3];
    float ss = 0.f;
#pragma unroll
    for (int i = 0; i < 3; ++i) {
        v[i] = xr[t + 256 * i];
        ss += v[i] * v[i];
    }
#pragma unroll
    for (int off = 32; off > 0; off >>= 1) ss += __shfl_down(ss, off);
    __shared__ float wss[4];
    const int lane = t & 63, wv = t >> 6;
    if (lane == 0) wss[wv] = ss;
    __syncthreads();
    const float tot = wss[0] + wss[1] + wss[2] + wss[3];
    const float inv = 1.0f / fmaxf(sqrtf(tot), 1e-8f);
#pragma unroll
    for (int i = 0; i < 3; ++i)
        xn[(long)row * KD + t + 256 * i] = __float2bfloat16(v[i] * inv);
}

// ---------------- Kernel 2: 256x128-tile 4-phase GEMM, fused Linear(1,2) ----------------
// 512 blocks = 2 sequential rounds/CU: round-2 compute overlaps round-1 write drain.
// 8 waves (2M x 4N), per-wave output 128x32 (8 M-frags x 2 N-frags of 16x16).
// LDS 96 KB: dbuf A[256][64] + B[128][64] bf16, G4 XOR-swizzle (T2).
// Units/K-tile: A.h0 (rows 0-127), A.h1 (rows 128-255), B.f (128 rows). 2 loads each.
// Issues (tile t): ph1 -> B.f(t+1) [other buf, safe];
//                  ph4 -> A.h0(t+2), A.h1(t+2) [same buf as t; A-reads done at ph3 close-bar].
// Boundary: vmcnt(4) waits exactly tile t+1's 6 ops (FIFO), keeps A(t+2) in flight.
__global__ __launch_bounds__(512, 2) void sim_gemm8(
    const bf16_t* __restrict__ Xn,
    const float* __restrict__ fcw, const float* __restrict__ fcb,
    float* __restrict__ out)
{
    __shared__ __align__(16) bf16_t Ab[2][BM * 64];  // 2 x 32 KB
    __shared__ __align__(16) bf16_t Bb[2][BN * 64];  // 2 x 16 KB

    const int tid = threadIdx.x;
    const int wv  = tid >> 6;   // 0..7
    const int ln  = tid & 63;
    const int wm  = wv >> 2;    // 0..1 (M group, 128 rows)
    const int wn  = wv & 3;     // 0..3 (N group, 32 cols)

    // XCD-chunked decode: hw XCD = blockIdx%8; each XCD gets a 4bi x 8bj subgrid
    // per round (WS = 4*393KB A + 8*197KB B = 3.1MB <= 4MB L2). Bijective.
    const int b = blockIdx.x;
    const int x = b & 7;
    const int s = b >> 3;
    const int round = s >> 5;      // 0..1 (first 256 blocks dispatch first)
    const int slot  = s & 31;
    const int bi = round * 8 + (x & 1) * 4 + (slot & 3);   // 0..15
    const int bj = (x >> 1) * 8 + (slot >> 2);             // 0..31
    const long Arow0 = (long)bi * BM, Brow0 = (long)bj * BN;

    // --- staging address precompute: 16KB chunk, dest byte = i*8192 + wv*1024 + ln*16
    //     source = SWZ(d): row = d>>7, kbyte = (d&127) ^ ((row&7)<<4) (involution) ---
    int rloc[2], scole[2];
#pragma unroll
    for (int i = 0; i < 2; ++i) {
        const int d = i * 8192 + wv * 1024 + ln * 16;
        rloc[i]  = d >> 7;                                   // 0..127
        scole[i] = ((d & 127) ^ ((rloc[i] & 7) << 4)) >> 1;  // elem offset in 64-elem row
    }

#define ISSUE_A(h, tt) do {                                                  \
        _Pragma("unroll")                                                    \
        for (int i_ = 0; i_ < 2; ++i_) {                                     \
            const bf16_t* g_ = Xn + (Arow0 + (h) * 128 + rloc[i_]) * (long)KD \
                               + (tt) * 64 + scole[i_];                      \
            bf16_t* l_ = &Ab[(tt) & 1][0]                                    \
                         + ((h) * 16384 + i_ * 8192 + wv * 1024) / 2;        \
            GLOAD_LDS16(g_, l_);                                             \
        }                                                                    \
    } while (0)

#define ISSUE_B(tt) do {                                                     \
        _Pragma("unroll")                                                    \
        for (int i_ = 0; i_ < 2; ++i_) {                                     \
            const bf16_t* g_ = Xn + (Brow0 + rloc[i_]) * (long)KD            \
                               + (tt) * 64 + scole[i_];                      \
            bf16_t* l_ = &Bb[(tt) & 1][0] + (i_ * 8192 + wv * 1024) / 2;     \
            GLOAD_LDS16(g_, l_);                                             \
        }                                                                    \
    } while (0)

    // --- ds_read: element (row,k) at swizzled byte row*128 + ((ks*64+hi16)^swzm) ---
    const int hi16 = (ln >> 4) << 4;
    const int swzm = (ln & 7) << 4;
    const int ke0 = ((0  + hi16) ^ swzm) >> 1;
    const int ke1 = ((64 + hi16) ^ swzm) >> 1;
    const int fr  = ln & 15;

    f32x4 acc[8][2] = {};
    bf16x8 a[4][2], b0[2], b1[2];

#define LDA(MH) do {                                                         \
        _Pragma("unroll")                                                    \
        for (int mf = 0; mf < 4; ++mf) {                                     \
            const int r_ = (wm * 128 + (MH) * 64 + mf * 16 + fr) * 64;       \
            a[mf][0] = *(const bf16x8*)&Ab[bb][r_ + ke0];                    \
            a[mf][1] = *(const bf16x8*)&Ab[bb][r_ + ke1];                    \
        }                                                                    \
    } while (0)

#define LDB(dst, NH) do {                                                    \
        const int r_ = (wn * 32 + (NH) * 16 + fr) * 64;                      \
        dst[0] = *(const bf16x8*)&Bb[bb][r_ + ke0];                          \
        dst[1] = *(const bf16x8*)&Bb[bb][r_ + ke1];                          \
    } while (0)

#define MMA(MH, NH, B_) do {                                                 \
        __builtin_amdgcn_s_setprio(1);                                       \
        _Pragma("unroll")                                                    \
        for (int mf = 0; mf < 4; ++mf)                                       \
        _Pragma("unroll")                                                    \
        for (int ks = 0; ks < 2; ++ks)                                       \
            acc[(MH)*4+mf][NH] = __builtin_amdgcn_mfma_f32_16x16x32_bf16(    \
                a[mf][ks], B_[ks], acc[(MH)*4+mf][NH], 0, 0, 0);             \
        __builtin_amdgcn_s_setprio(0);                                       \
    } while (0)

    // --- prologue: tile0 fully + A(1) in flight -> steady-state invariant ---
    ISSUE_A(0, 0); ISSUE_A(1, 0); ISSUE_B(0);   // 6 ops
    ISSUE_A(0, 1); ISSUE_A(1, 1);               // 4 ops
    asm volatile("s_waitcnt vmcnt(4)" ::: "memory");  // tile0 landed; A(1) in flight
    BAR();

    for (int t = 0; t < NT; ++t) {
        const int bb = t & 1;

        // ph1: quadrant (M0,N0)
        LDA(0); LDB(b0, 0);
        if (t + 1 < NT) ISSUE_B(t + 1);
        BAR(); LGKM0();
        MMA(0, 0, b0);
        BAR();

        // ph2: quadrant (M0,N1)
        LDB(b1, 1);
        BAR(); LGKM0();
        MMA(0, 1, b1);
        BAR();

        // ph3: quadrant (M1,N1)
        LDA(1);
        BAR(); LGKM0();
        MMA(1, 1, b1);
        BAR();

        // ph4: quadrant (M1,N0) — no new ds_reads; A-reads of t done at ph3 close-bar
        if (t + 2 < NT) { ISSUE_A(0, t + 2); ISSUE_A(1, t + 2); }
        BAR();
        MMA(1, 0, b0);
        if (t + 2 < NT)      asm volatile("s_waitcnt vmcnt(4)" ::: "memory");
        else if (t + 1 < NT) asm volatile("s_waitcnt vmcnt(0)" ::: "memory");
        BAR();
    }

    // --- epilogue: fused Linear(1,2), coalesced float2 stores ---
    const float w0 = fcw[0], w1 = fcw[1];
    const float c0 = fcb[0], c1 = fcb[1];
    const long row0 = Arow0 + wm * 128 + ((ln >> 4) << 2);
    const int  col0 = (int)Brow0 + wn * 32 + fr;
#pragma unroll
    for (int mi = 0; mi < 8; ++mi)
#pragma unroll
        for (int ni = 0; ni < 2; ++ni) {
            const int col = col0 + ni * 16;
#pragma unroll
            for (int r = 0; r < 4; ++r) {
                const long row = row0 + mi * 16 + r;
                const float sv = acc[mi][ni][r];
                *(float2*)&out[(row * BDIM + col) * 2] =
                    make_float2(fmaf(sv, w0, c0), fmaf(sv, w1, c1));
            }
        }

#undef ISSUE_A
#undef ISSUE_B
#undef LDA
#undef LDB
#undef MMA
}

extern "C" void kernel_launch(void* const* d_in, const int* in_sizes, int n_in,
                              void* d_out, int out_size, void* d_ws, size_t ws_size,
                              hipStream_t stream) {
    const float* x   = (const float*)d_in[0];
    const float* fcw = (const float*)d_in[1];
    const float* fcb = (const float*)d_in[2];
    float* out = (float*)d_out;

    __hip_bfloat16* xn = (__hip_bfloat16*)d_ws;  // 4096*768*2B = 6.3 MB

    normalize_rows<<<BDIM, 256, 0, stream>>>(x, xn);

    sim_gemm8<<<(BDIM / BM) * (BDIM / BN), 512, 0, stream>>>(
        (const bf16_t*)xn, fcw, fcb, out);
}

// Round 5
// 61.092 us; speedup vs baseline: 1.0164x; 1.0164x over previous
//
#include <hip/hip_runtime.h>
#include <hip/hip_bf16.h>

typedef __bf16 bf16_t;
typedef bf16_t bf16x8 __attribute__((ext_vector_type(8)));
typedef float f32x4 __attribute__((ext_vector_type(4)));
typedef float f32x2 __attribute__((ext_vector_type(2)));

#define KD 768
#define BDIM 4096
#define NT 12        // K-tiles of BK=64
#define BM 256

#define GLOAD_LDS16(gptr, lptr)                                             \
    __builtin_amdgcn_global_load_lds(                                       \
        (const __attribute__((address_space(1))) unsigned int*)(gptr),      \
        (__attribute__((address_space(3))) unsigned int*)(lptr), 16, 0, 0)

#define BAR()   __builtin_amdgcn_s_barrier()
#define LGKM0() asm volatile("s_waitcnt lgkmcnt(0)" ::: "memory")

// ---------------- Kernel 1: row-normalize fp32 -> bf16 ----------------
__global__ __launch_bounds__(256) void normalize_rows(
    const float* __restrict__ x, __hip_bfloat16* __restrict__ xn)
{
    const int row = blockIdx.x;
    const int t = threadIdx.x;
    const float* xr = x + (long)row * KD;

    float v[3];
    float ss = 0.f;
#pragma unroll
    for (int i = 0; i < 3; ++i) {
        v[i] = xr[t + 256 * i];
        ss += v[i] * v[i];
    }
#pragma unroll
    for (int off = 32; off > 0; off >>= 1) ss += __shfl_down(ss, off);
    __shared__ float wss[4];
    const int lane = t & 63, wv = t >> 6;
    if (lane == 0) wss[wv] = ss;
    __syncthreads();
    const float tot = wss[0] + wss[1] + wss[2] + wss[3];
    const float inv = 1.0f / fmaxf(sqrtf(tot), 1e-8f);
#pragma unroll
    for (int i = 0; i < 3; ++i)
        xn[(long)row * KD + t + 256 * i] = __float2bfloat16(v[i] * inv);
}

// ---------------- Kernel 2: 256x256-tile 8-phase GEMM, fused Linear(1,2) ----------------
// R3-verified schedule, unchanged. New vs R3: (1) XCD-chunked block decode
// (hw XCD = blockIdx&7): each XCD owns a 4bi x 8bj sub-grid -> 4.7 MB working set
// ~L2-resident; (2) nontemporal epilogue stores (output never re-read; don't evict Xn).
__global__ __launch_bounds__(512, 2) void sim_gemm8(
    const bf16_t* __restrict__ Xn,
    const float* __restrict__ fcw, const float* __restrict__ fcb,
    float* __restrict__ out)
{
    __shared__ __align__(16) bf16_t Ab[2][BM * 64];  // 2 x 32 KB
    __shared__ __align__(16) bf16_t Bb[2][BM * 64];  // 2 x 32 KB

    const int tid = threadIdx.x;
    const int wv  = tid >> 6;   // 0..7
    const int ln  = tid & 63;
    const int wm  = wv >> 2;    // 0..1 (M group)
    const int wn  = wv & 3;     // 0..3 (N group)

    // XCD-chunked decode: xcd = b&7 (hw round-robin). XCDs tile the 16x16 grid
    // as 4x2 super-blocks of 4bi x 8bj. Bijective.
    const int b = blockIdx.x;
    const int x = b & 7;
    const int s = b >> 3;                     // 0..31
    const int bi = (x >> 1) * 4 + (s & 3);    // 0..15
    const int bj = (x & 1) * 8 + (s >> 2);    // 0..15
    const long Arow0 = (long)bi * BM, Brow0 = (long)bj * BM;

    // --- staging address precompute (per thread) ---
    // Linear dest byte within 32KB tile: d = hr*16384 + i*8192 + wv*1024 + ln*16.
    // Source element = SWZ(d) where SWZ(b) = b ^ (((b>>7)&7)<<4) (involution).
    int srow[2][2], scole[2][2];
#pragma unroll
    for (int hr = 0; hr < 2; ++hr)
#pragma unroll
        for (int i = 0; i < 2; ++i) {
            const int d = hr * 16384 + i * 8192 + wv * 1024 + ln * 16;
            const int sw = d ^ (((d >> 7) & 7) << 4);
            srow[hr][i]  = sw >> 7;         // 0..255 within tile
            scole[hr][i] = (sw & 127) >> 1; // element offset within 64-elem row
        }

#define ISSUE_HALF(h, tt) do {                                               \
        const int hr_ = (h) & 1;                                             \
        const int bb_ = (tt) & 1;                                            \
        const long rb_ = ((h) < 2 ? Arow0 : Brow0);                          \
        bf16_t* lb_ = ((h) < 2 ? &Ab[bb_][0] : &Bb[bb_][0]);                 \
        _Pragma("unroll")                                                    \
        for (int i_ = 0; i_ < 2; ++i_) {                                     \
            const bf16_t* g_ = Xn + (rb_ + srow[hr_][i_]) * (long)KD         \
                               + (tt) * 64 + scole[hr_][i_];                 \
            bf16_t* l_ = lb_ + (hr_ * 16384 + i_ * 8192 + wv * 1024) / 2;    \
            GLOAD_LDS16(g_, l_);                                             \
        }                                                                    \
    } while (0)

    // --- ds_read addressing: element (row, k) at swizzled byte
    //     row*128 + ((ks*64 + (ln>>4)*16) ^ ((ln&7)<<4)) ---
    const int hi16 = (ln >> 4) << 4;
    const int swzm = (ln & 7) << 4;
    const int ke0 = ((0  + hi16) ^ swzm) >> 1;  // elem offset, ks=0
    const int ke1 = ((64 + hi16) ^ swzm) >> 1;  // elem offset, ks=1
    const int fr  = ln & 15;

    f32x4 acc[8][4] = {};
    bf16x8 a[4][2], b0[2][2], b1[2][2];

#define LDA(MH) do {                                                         \
        _Pragma("unroll")                                                    \
        for (int mf = 0; mf < 4; ++mf) {                                     \
            const int r_ = (wm * 128 + (MH) * 64 + mf * 16 + fr) * 64;       \
            a[mf][0] = *(const bf16x8*)&Ab[bb][r_ + ke0];                    \
            a[mf][1] = *(const bf16x8*)&Ab[bb][r_ + ke1];                    \
        }                                                                    \
    } while (0)

#define LDB(dst, NH) do {                                                    \
        _Pragma("unroll")                                                    \
        for (int nf = 0; nf < 2; ++nf) {                                     \
            const int r_ = (wn * 64 + (NH) * 32 + nf * 16 + fr) * 64;        \
            dst[nf][0] = *(const bf16x8*)&Bb[bb][r_ + ke0];                  \
            dst[nf][1] = *(const bf16x8*)&Bb[bb][r_ + ke1];                  \
        }                                                                    \
    } while (0)

#define MMA(MH, NH, B_) do {                                                 \
        __builtin_amdgcn_s_setprio(1);                                       \
        _Pragma("unroll")                                                    \
        for (int mf = 0; mf < 4; ++mf)                                       \
        _Pragma("unroll")                                                    \
        for (int nf = 0; nf < 2; ++nf)                                       \
        _Pragma("unroll")                                                    \
        for (int ks = 0; ks < 2; ++ks)                                       \
            acc[(MH)*4+mf][(NH)*2+nf] = __builtin_amdgcn_mfma_f32_16x16x32_bf16( \
                a[mf][ks], B_[nf][ks], acc[(MH)*4+mf][(NH)*2+nf], 0, 0, 0);  \
        __builtin_amdgcn_s_setprio(0);                                       \
    } while (0)

    // --- prologue: tile0 all 4 halves + tile1 {h2, h0} ---
    ISSUE_HALF(0, 0); ISSUE_HALF(1, 0); ISSUE_HALF(2, 0); ISSUE_HALF(3, 0);
    ISSUE_HALF(2, 1); ISSUE_HALF(0, 1);
    asm volatile("s_waitcnt vmcnt(4)" ::: "memory");  // tile0 landed; tile1 halves in flight
    BAR();

    for (int t = 0; t < NT; ++t) {
        const int bb = t & 1;

        // phase 1: quadrant (M0, N0)
        LDA(0); LDB(b0, 0);
        if (t + 1 < NT) ISSUE_HALF(1, t + 1);
        BAR(); LGKM0();
        MMA(0, 0, b0);
        BAR();

        // phase 2: quadrant (M0, N1)
        LDB(b1, 1);
        if (t + 1 < NT) ISSUE_HALF(3, t + 1);
        BAR(); LGKM0();
        MMA(0, 1, b1);
        BAR();

        // phase 3: quadrant (M1, N1)
        LDA(1);
        if (t + 2 < NT) ISSUE_HALF(2, t + 2);
        BAR(); LGKM0();
        MMA(1, 1, b1);
        BAR();

        // phase 4: quadrant (M1, N0) — no new ds_reads (b0 kept in regs)
        if (t + 2 < NT) ISSUE_HALF(0, t + 2);
        BAR(); LGKM0();
        MMA(1, 0, b0);
        if (t + 2 < NT)      asm volatile("s_waitcnt vmcnt(4)" ::: "memory");
        else if (t + 1 < NT) asm volatile("s_waitcnt vmcnt(0)" ::: "memory");
        BAR();
    }

    // --- epilogue: fused Linear(1,2), coalesced nontemporal float2 stores ---
    const float w0 = fcw[0], w1 = fcw[1];
    const float c0 = fcb[0], c1 = fcb[1];
    const long row0 = Arow0 + wm * 128 + ((ln >> 4) << 2);
    const int  col0 = (int)Brow0 + wn * 64 + fr;
#pragma unroll
    for (int mi = 0; mi < 8; ++mi)
#pragma unroll
        for (int ni = 0; ni < 4; ++ni) {
            const int col = col0 + ni * 16;
#pragma unroll
            for (int r = 0; r < 4; ++r) {
                const long row = row0 + mi * 16 + r;
                const float sv = acc[mi][ni][r];
                f32x2 v; v.x = fmaf(sv, w0, c0); v.y = fmaf(sv, w1, c1);
                __builtin_nontemporal_store(v, (f32x2*)&out[(row * BDIM + col) * 2]);
            }
        }

#undef ISSUE_HALF
#undef LDA
#undef LDB
#undef MMA
}

extern "C" void kernel_launch(void* const* d_in, const int* in_sizes, int n_in,
                              void* d_out, int out_size, void* d_ws, size_t ws_size,
                              hipStream_t stream) {
    const float* x   = (const float*)d_in[0];
    const float* fcw = (const float*)d_in[1];
    const float* fcb = (const float*)d_in[2];
    float* out = (float*)d_out;

    __hip_bfloat16* xn = (__hip_bfloat16*)d_ws;  // 4096*768*2B = 6.3 MB

    normalize_rows<<<BDIM, 256, 0, stream>>>(x, xn);

    sim_gemm8<<<(BDIM / BM) * (BDIM / BM), 512, 0, stream>>>(
        (const bf16_t*)xn, fcw, fcb, out);
}

// Round 6
// 55.503 us; speedup vs baseline: 1.1187x; 1.1007x over previous
//
#include <hip/hip_runtime.h>
#include <hip/hip_bf16.h>

typedef __bf16 bf16_t;
typedef bf16_t bf16x8 __attribute__((ext_vector_type(8)));
typedef float f32x4 __attribute__((ext_vector_type(4)));

#define KD 768
#define BDIM 4096
#define NT 12        // K-tiles of BK=64
#define BM 256

#define GLOAD_LDS16(gptr, lptr)                                             \
    __builtin_amdgcn_global_load_lds(                                       \
        (const __attribute__((address_space(1))) unsigned int*)(gptr),      \
        (__attribute__((address_space(3))) unsigned int*)(lptr), 16, 0, 0)

#define BAR()   __builtin_amdgcn_s_barrier()
#define LGKM0() asm volatile("s_waitcnt lgkmcnt(0)" ::: "memory")

// ---------------- Kernel 1: row-normalize fp32 -> bf16 ----------------
__global__ __launch_bounds__(256) void normalize_rows(
    const float* __restrict__ x, __hip_bfloat16* __restrict__ xn)
{
    const int row = blockIdx.x;
    const int t = threadIdx.x;
    const float* xr = x + (long)row * KD;

    float v[3];
    float ss = 0.f;
#pragma unroll
    for (int i = 0; i < 3; ++i) {
        v[i] = xr[t + 256 * i];
        ss += v[i] * v[i];
    }
#pragma unroll
    for (int off = 32; off > 0; off >>= 1) ss += __shfl_down(ss, off);
    __shared__ float wss[4];
    const int lane = t & 63, wv = t >> 6;
    if (lane == 0) wss[wv] = ss;
    __syncthreads();
    const float tot = wss[0] + wss[1] + wss[2] + wss[3];
    const float inv = 1.0f / fmaxf(sqrtf(tot), 1e-8f);
#pragma unroll
    for (int i = 0; i < 3; ++i)
        xn[(long)row * KD + t + 256 * i] = __float2bfloat16(v[i] * inv);
}

// ---------------- Kernel 2: 256x256-tile 8-phase GEMM, fused Linear(1,2) ----------------
// R3-verified schedule, byte-identical K-loop and epilogue (plain float2 stores).
// ONLY change vs R3: XCD-chunked block decode. hw XCD = blockIdx&7 (m09 round-robin).
// Each XCD owns a 4bi x 8bj region, split into 2 sub-rounds of 4bi x 4bj:
// working set 8 panels x 393KB = 3.1MB <= 4MB XCD L2. Sub-round 0 = blockIdx 0..127,
// dispatched first. Bijective (inverse: x=(bi>>2)*2+(bj>>3), r=(bj>>2)&1).
__global__ __launch_bounds__(512, 2) void sim_gemm8(
    const bf16_t* __restrict__ Xn,
    const float* __restrict__ fcw, const float* __restrict__ fcb,
    float* __restrict__ out)
{
    __shared__ __align__(16) bf16_t Ab[2][BM * 64];  // 2 x 32 KB
    __shared__ __align__(16) bf16_t Bb[2][BM * 64];  // 2 x 32 KB

    const int tid = threadIdx.x;
    const int wv  = tid >> 6;   // 0..7
    const int ln  = tid & 63;
    const int wm  = wv >> 2;    // 0..1 (M group)
    const int wn  = wv & 3;     // 0..3 (N group)

    // XCD-chunked decode (see header comment)
    const int b  = blockIdx.x;
    const int x  = b & 7;
    const int s  = b >> 3;        // 0..31
    const int r  = s >> 4;        // sub-round 0/1
    const int sp = s & 15;
    const int bi = (x >> 1) * 4 + (sp & 3);            // 0..15
    const int bj = (x & 1) * 8 + r * 4 + (sp >> 2);    // 0..15
    const long Arow0 = (long)bi * BM, Brow0 = (long)bj * BM;

    // --- staging address precompute (per thread) ---
    // Linear dest byte within 32KB tile: d = hr*16384 + i*8192 + wv*1024 + ln*16.
    // Source element = SWZ(d) where SWZ(b) = b ^ (((b>>7)&7)<<4) (involution).
    int srow[2][2], scole[2][2];
#pragma unroll
    for (int hr = 0; hr < 2; ++hr)
#pragma unroll
        for (int i = 0; i < 2; ++i) {
            const int d = hr * 16384 + i * 8192 + wv * 1024 + ln * 16;
            const int sw = d ^ (((d >> 7) & 7) << 4);
            srow[hr][i]  = sw >> 7;         // 0..255 within tile
            scole[hr][i] = (sw & 127) >> 1; // element offset within 64-elem row
        }

#define ISSUE_HALF(h, tt) do {                                               \
        const int hr_ = (h) & 1;                                             \
        const int bb_ = (tt) & 1;                                            \
        const long rb_ = ((h) < 2 ? Arow0 : Brow0);                          \
        bf16_t* lb_ = ((h) < 2 ? &Ab[bb_][0] : &Bb[bb_][0]);                 \
        _Pragma("unroll")                                                    \
        for (int i_ = 0; i_ < 2; ++i_) {                                     \
            const bf16_t* g_ = Xn + (rb_ + srow[hr_][i_]) * (long)KD         \
                               + (tt) * 64 + scole[hr_][i_];                 \
            bf16_t* l_ = lb_ + (hr_ * 16384 + i_ * 8192 + wv * 1024) / 2;    \
            GLOAD_LDS16(g_, l_);                                             \
        }                                                                    \
    } while (0)

    // --- ds_read addressing: element (row, k) at swizzled byte
    //     row*128 + ((ks*64 + (ln>>4)*16) ^ ((ln&7)<<4)) ---
    const int hi16 = (ln >> 4) << 4;
    const int swzm = (ln & 7) << 4;
    const int ke0 = ((0  + hi16) ^ swzm) >> 1;  // elem offset, ks=0
    const int ke1 = ((64 + hi16) ^ swzm) >> 1;  // elem offset, ks=1
    const int fr  = ln & 15;

    f32x4 acc[8][4] = {};
    bf16x8 a[4][2], b0[2][2], b1[2][2];

#define LDA(MH) do {                                                         \
        _Pragma("unroll")                                                    \
        for (int mf = 0; mf < 4; ++mf) {                                     \
            const int r_ = (wm * 128 + (MH) * 64 + mf * 16 + fr) * 64;       \
            a[mf][0] = *(const bf16x8*)&Ab[bb][r_ + ke0];                    \
            a[mf][1] = *(const bf16x8*)&Ab[bb][r_ + ke1];                    \
        }                                                                    \
    } while (0)

#define LDB(dst, NH) do {                                                    \
        _Pragma("unroll")                                                    \
        for (int nf = 0; nf < 2; ++nf) {                                     \
            const int r_ = (wn * 64 + (NH) * 32 + nf * 16 + fr) * 64;        \
            dst[nf][0] = *(const bf16x8*)&Bb[bb][r_ + ke0];                  \
            dst[nf][1] = *(const bf16x8*)&Bb[bb][r_ + ke1];                  \
        }                                                                    \
    } while (0)

#define MMA(MH, NH, B_) do {                                                 \
        __builtin_amdgcn_s_setprio(1);                                       \
        _Pragma("unroll")                                                    \
        for (int mf = 0; mf < 4; ++mf)                                       \
        _Pragma("unroll")                                                    \
        for (int nf = 0; nf < 2; ++nf)                                       \
        _Pragma("unroll")                                                    \
        for (int ks = 0; ks < 2; ++ks)                                       \
            acc[(MH)*4+mf][(NH)*2+nf] = __builtin_amdgcn_mfma_f32_16x16x32_bf16( \
                a[mf][ks], B_[nf][ks], acc[(MH)*4+mf][(NH)*2+nf], 0, 0, 0);  \
        __builtin_amdgcn_s_setprio(0);                                       \
    } while (0)

    // --- prologue: tile0 all 4 halves + tile1 {h2, h0} ---
    ISSUE_HALF(0, 0); ISSUE_HALF(1, 0); ISSUE_HALF(2, 0); ISSUE_HALF(3, 0);
    ISSUE_HALF(2, 1); ISSUE_HALF(0, 1);
    asm volatile("s_waitcnt vmcnt(4)" ::: "memory");  // tile0 landed; tile1 halves in flight
    BAR();

    for (int t = 0; t < NT; ++t) {
        const int bb = t & 1;

        // phase 1: quadrant (M0, N0)
        LDA(0); LDB(b0, 0);
        if (t + 1 < NT) ISSUE_HALF(1, t + 1);
        BAR(); LGKM0();
        MMA(0, 0, b0);
        BAR();

        // phase 2: quadrant (M0, N1)
        LDB(b1, 1);
        if (t + 1 < NT) ISSUE_HALF(3, t + 1);
        BAR(); LGKM0();
        MMA(0, 1, b1);
        BAR();

        // phase 3: quadrant (M1, N1)
        LDA(1);
        if (t + 2 < NT) ISSUE_HALF(2, t + 2);
        BAR(); LGKM0();
        MMA(1, 1, b1);
        BAR();

        // phase 4: quadrant (M1, N0) — no new ds_reads (b0 kept in regs)
        if (t + 2 < NT) ISSUE_HALF(0, t + 2);
        BAR(); LGKM0();
        MMA(1, 0, b0);
        if (t + 2 < NT)      asm volatile("s_waitcnt vmcnt(4)" ::: "memory");
        else if (t + 1 < NT) asm volatile("s_waitcnt vmcnt(0)" ::: "memory");
        BAR();
    }

    // --- epilogue: fused Linear(1,2), coalesced float2 stores ---
    const float w0 = fcw[0], w1 = fcw[1];
    const float c0 = fcb[0], c1 = fcb[1];
    const long row0 = Arow0 + wm * 128 + ((ln >> 4) << 2);
    const int  col0 = (int)Brow0 + wn * 64 + fr;
#pragma unroll
    for (int mi = 0; mi < 8; ++mi)
#pragma unroll
        for (int ni = 0; ni < 4; ++ni) {
            const int col = col0 + ni * 16;
#pragma unroll
            for (int rr = 0; rr < 4; ++rr) {
                const long row = row0 + mi * 16 + rr;
                const float sv = acc[mi][ni][rr];
                *(float2*)&out[(row * BDIM + col) * 2] =
                    make_float2(fmaf(sv, w0, c0), fmaf(sv, w1, c1));
            }
        }

#undef ISSUE_HALF
#undef LDA
#undef LDB
#undef MMA
}

extern "C" void kernel_launch(void* const* d_in, const int* in_sizes, int n_in,
                              void* d_out, int out_size, void* d_ws, size_t ws_size,
                              hipStream_t stream) {
    const float* x   = (const float*)d_in[0];
    const float* fcw = (const float*)d_in[1];
    const float* fcb = (const float*)d_in[2];
    float* out = (float*)d_out;

    __hip_bfloat16* xn = (__hip_bfloat16*)d_ws;  // 4096*768*2B = 6.3 MB

    normalize_rows<<<BDIM, 256, 0, stream>>>(x, xn);

    sim_gemm8<<<(BDIM / BM) * (BDIM / BM), 512, 0, stream>>>(
        (const bf16_t*)xn, fcw, fcb, out);
}

// Round 7
// 54.991 us; speedup vs baseline: 1.1291x; 1.0093x over previous
//
#include <hip/hip_runtime.h>
#include <hip/hip_bf16.h>

typedef __bf16 bf16_t;
typedef bf16_t bf16x8 __attribute__((ext_vector_type(8)));
typedef float f32x4 __attribute__((ext_vector_type(4)));

#define KD 768
#define BDIM 4096
#define NT 12        // K-tiles of BK=64
#define BM 256

#define GLOAD_LDS16(gptr, lptr)                                             \
    __builtin_amdgcn_global_load_lds(                                       \
        (const __attribute__((address_space(1))) unsigned int*)(gptr),      \
        (__attribute__((address_space(3))) unsigned int*)(lptr), 16, 0, 0)

// hw barrier + compiler memory fence, NO waitcnt drain (unlike __syncthreads)
#define FBAR() asm volatile("s_barrier" ::: "memory")

// ---------------- Kernel 1: row-normalize fp32 -> bf16 ----------------
__global__ __launch_bounds__(256) void normalize_rows(
    const float* __restrict__ x, __hip_bfloat16* __restrict__ xn)
{
    const int row = blockIdx.x;
    const int t = threadIdx.x;
    const float* xr = x + (long)row * KD;

    float v[3];
    float ss = 0.f;
#pragma unroll
    for (int i = 0; i < 3; ++i) {
        v[i] = xr[t + 256 * i];
        ss += v[i] * v[i];
    }
#pragma unroll
    for (int off = 32; off > 0; off >>= 1) ss += __shfl_down(ss, off);
    __shared__ float wss[4];
    const int lane = t & 63, wv = t >> 6;
    if (lane == 0) wss[wv] = ss;
    __syncthreads();
    const float tot = wss[0] + wss[1] + wss[2] + wss[3];
    const float inv = 1.0f / fmaxf(sqrtf(tot), 1e-8f);
#pragma unroll
    for (int i = 0; i < 3; ++i)
        xn[(long)row * KD + t + 256 * i] = __float2bfloat16(v[i] * inv);
}

// ---------------- Kernel 2: 256x256-tile GEMM, 2-barrier K-tiles, fused Linear(1,2) ----
// vs R6: per-phase barriers REMOVED. Per K-tile: loads+MFMA in program order
// (compiler emits counted lgkmcnt for ds_read->MFMA), then exactly 2 sync points:
//   FBAR#1 after last MFMA of tile t  -> all waves' reads of buffer bb complete
//                                        (MFMA issue implies operand lgkmcnt satisfied)
//   issue t+2 staging into bb (safe), vmcnt(8) -> t+1's 8 loads landed (FIFO), FBAR#2.
// Staging: all 8 gload_lds per tile issued 2 tiles ahead. No latency-window reliance.
__global__ __launch_bounds__(512, 2) void sim_gemm8(
    const bf16_t* __restrict__ Xn,
    const float* __restrict__ fcw, const float* __restrict__ fcb,
    float* __restrict__ out)
{
    __shared__ __align__(16) bf16_t Ab[2][BM * 64];  // 2 x 32 KB
    __shared__ __align__(16) bf16_t Bb[2][BM * 64];  // 2 x 32 KB

    const int tid = threadIdx.x;
    const int wv  = tid >> 6;   // 0..7
    const int ln  = tid & 63;
    const int wm  = wv >> 2;    // 0..1 (M group)
    const int wn  = wv & 3;     // 0..3 (N group)

    // XCD-chunked decode (kept from R6; proven neutral, bijective)
    const int b  = blockIdx.x;
    const int x  = b & 7;
    const int s  = b >> 3;        // 0..31
    const int r  = s >> 4;        // sub-round 0/1
    const int sp = s & 15;
    const int bi = (x >> 1) * 4 + (sp & 3);            // 0..15
    const int bj = (x & 1) * 8 + r * 4 + (sp >> 2);    // 0..15
    const long Arow0 = (long)bi * BM, Brow0 = (long)bj * BM;

    // --- staging address precompute (per thread) ---
    // Linear dest byte within 32KB tile: d = hr*16384 + i*8192 + wv*1024 + ln*16.
    // Source element = SWZ(d) where SWZ(b) = b ^ (((b>>7)&7)<<4) (involution).
    int srow[2][2], scole[2][2];
#pragma unroll
    for (int hr = 0; hr < 2; ++hr)
#pragma unroll
        for (int i = 0; i < 2; ++i) {
            const int d = hr * 16384 + i * 8192 + wv * 1024 + ln * 16;
            const int sw = d ^ (((d >> 7) & 7) << 4);
            srow[hr][i]  = sw >> 7;         // 0..255 within tile
            scole[hr][i] = (sw & 127) >> 1; // element offset within 64-elem row
        }

#define ISSUE_HALF(h, tt) do {                                               \
        const int hr_ = (h) & 1;                                             \
        const int bb_ = (tt) & 1;                                            \
        const long rb_ = ((h) < 2 ? Arow0 : Brow0);                          \
        bf16_t* lb_ = ((h) < 2 ? &Ab[bb_][0] : &Bb[bb_][0]);                 \
        _Pragma("unroll")                                                    \
        for (int i_ = 0; i_ < 2; ++i_) {                                     \
            const bf16_t* g_ = Xn + (rb_ + srow[hr_][i_]) * (long)KD         \
                               + (tt) * 64 + scole[hr_][i_];                 \
            bf16_t* l_ = lb_ + (hr_ * 16384 + i_ * 8192 + wv * 1024) / 2;    \
            GLOAD_LDS16(g_, l_);                                             \
        }                                                                    \
    } while (0)

#define ISSUE_TILE(tt) do {                                                  \
        ISSUE_HALF(0, tt); ISSUE_HALF(1, tt);                                \
        ISSUE_HALF(2, tt); ISSUE_HALF(3, tt);                                \
    } while (0)

    // --- ds_read addressing: element (row, k) at swizzled byte
    //     row*128 + ((ks*64 + (ln>>4)*16) ^ ((ln&7)<<4)) ---
    const int hi16 = (ln >> 4) << 4;
    const int swzm = (ln & 7) << 4;
    const int ke0 = ((0  + hi16) ^ swzm) >> 1;  // elem offset, ks=0
    const int ke1 = ((64 + hi16) ^ swzm) >> 1;  // elem offset, ks=1
    const int fr  = ln & 15;

    f32x4 acc[8][4] = {};
    bf16x8 a[4][2], b0[2][2], b1[2][2];

#define LDA(MH) do {                                                         \
        _Pragma("unroll")                                                    \
        for (int mf = 0; mf < 4; ++mf) {                                     \
            const int r_ = (wm * 128 + (MH) * 64 + mf * 16 + fr) * 64;       \
            a[mf][0] = *(const bf16x8*)&Ab[bb][r_ + ke0];                    \
            a[mf][1] = *(const bf16x8*)&Ab[bb][r_ + ke1];                    \
        }                                                                    \
    } while (0)

#define LDB(dst, NH) do {                                                    \
        _Pragma("unroll")                                                    \
        for (int nf = 0; nf < 2; ++nf) {                                     \
            const int r_ = (wn * 64 + (NH) * 32 + nf * 16 + fr) * 64;        \
            dst[nf][0] = *(const bf16x8*)&Bb[bb][r_ + ke0];                  \
            dst[nf][1] = *(const bf16x8*)&Bb[bb][r_ + ke1];                  \
        }                                                                    \
    } while (0)

#define MMA(MH, NH, B_) do {                                                 \
        __builtin_amdgcn_s_setprio(1);                                       \
        _Pragma("unroll")                                                    \
        for (int mf = 0; mf < 4; ++mf)                                       \
        _Pragma("unroll")                                                    \
        for (int nf = 0; nf < 2; ++nf)                                       \
        _Pragma("unroll")                                                    \
        for (int ks = 0; ks < 2; ++ks)                                       \
            acc[(MH)*4+mf][(NH)*2+nf] = __builtin_amdgcn_mfma_f32_16x16x32_bf16( \
                a[mf][ks], B_[nf][ks], acc[(MH)*4+mf][(NH)*2+nf], 0, 0, 0);  \
        __builtin_amdgcn_s_setprio(0);                                       \
    } while (0)

    // --- prologue: stage tile0 + tile1 fully; tile0 landed, tile1 in flight ---
    ISSUE_TILE(0);   // 8 loads
    ISSUE_TILE(1);   // 8 loads
    asm volatile("s_waitcnt vmcnt(8)" ::: "memory");
    FBAR();

    for (int t = 0; t < NT; ++t) {
        const int bb = t & 1;

        // entire K-tile: loads + MFMA, no internal barriers.
        // Compiler inserts counted lgkmcnt between ds_read and dependent MFMA.
        LDA(0);              // 8 ds_read_b128 -> aM0
        LDB(b0, 0);          // 4
        LDB(b1, 1);          // 4
        MMA(0, 0, b0);       // 16 MFMA
        MMA(0, 1, b1);       // 16 MFMA
        LDA(1);              // 8 ds_read_b128 -> aM1 (reuses a[]; compiler renames)
        MMA(1, 1, b1);       // 16 MFMA
        MMA(1, 0, b0);       // 16 MFMA

        if (t + 1 == NT) break;  // last tile: straight to epilogue

        FBAR();  // all waves' reads of bb complete (MFMA issue => operands waited)
        if (t + 2 < NT) {
            ISSUE_TILE(t + 2);   // 8 loads into bb (now safe to overwrite)
            asm volatile("s_waitcnt vmcnt(8)" ::: "memory");  // t+1's 8 landed
        } else {
            asm volatile("s_waitcnt vmcnt(0)" ::: "memory");  // drain t+1
        }
        FBAR();  // all waves see bb^1 staged -> safe to read next iter
    }

    // --- epilogue: fused Linear(1,2), coalesced float2 stores ---
    const float w0 = fcw[0], w1 = fcw[1];
    const float c0 = fcb[0], c1 = fcb[1];
    const long row0 = Arow0 + wm * 128 + ((ln >> 4) << 2);
    const int  col0 = (int)Brow0 + wn * 64 + fr;
#pragma unroll
    for (int mi = 0; mi < 8; ++mi)
#pragma unroll
        for (int ni = 0; ni < 4; ++ni) {
            const int col = col0 + ni * 16;
#pragma unroll
            for (int rr = 0; rr < 4; ++rr) {
                const long row = row0 + mi * 16 + rr;
                const float sv = acc[mi][ni][rr];
                *(float2*)&out[(row * BDIM + col) * 2] =
                    make_float2(fmaf(sv, w0, c0), fmaf(sv, w1, c1));
            }
        }

#undef ISSUE_HALF
#undef ISSUE_TILE
#undef LDA
#undef LDB
#undef MMA
}

extern "C" void kernel_launch(void* const* d_in, const int* in_sizes, int n_in,
                              void* d_out, int out_size, void* d_ws, size_t ws_size,
                              hipStream_t stream) {
    const float* x   = (const float*)d_in[0];
    const float* fcw = (const float*)d_in[1];
    const float* fcb = (const float*)d_in[2];
    float* out = (float*)d_out;

    __hip_bfloat16* xn = (__hip_bfloat16*)d_ws;  // 4096*768*2B = 6.3 MB

    normalize_rows<<<BDIM, 256, 0, stream>>>(x, xn);

    sim_gemm8<<<(BDIM / BM) * (BDIM / BM), 512, 0, stream>>>(
        (const bf16_t*)xn, fcw, fcb, out);
}

// Round 8
// 52.729 us; speedup vs baseline: 1.1776x; 1.0429x over previous
//
#include <hip/hip_runtime.h>
#include <hip/hip_bf16.h>

typedef __bf16 bf16_t;
typedef bf16_t bf16x8 __attribute__((ext_vector_type(8)));
typedef float f32x4 __attribute__((ext_vector_type(4)));

#define KD 768
#define BDIM 4096
#define NT 12        // K-tiles of BK=64
#define BM 256

#define GLOAD_LDS16(gptr, lptr)                                             \
    __builtin_amdgcn_global_load_lds(                                       \
        (const __attribute__((address_space(1))) unsigned int*)(gptr),      \
        (__attribute__((address_space(3))) unsigned int*)(lptr), 16, 0, 0)

// hw barrier + compiler memory fence, NO waitcnt drain (unlike __syncthreads)
#define FBAR() asm volatile("s_barrier" ::: "memory")

// ---------------- Kernel 1: row-normalize fp32 -> bf16 ----------------
__global__ __launch_bounds__(256) void normalize_rows(
    const float* __restrict__ x, __hip_bfloat16* __restrict__ xn)
{
    const int row = blockIdx.x;
    const int t = threadIdx.x;
    const float* xr = x + (long)row * KD;

    float v[3];
    float ss = 0.f;
#pragma unroll
    for (int i = 0; i < 3; ++i) {
        v[i] = xr[t + 256 * i];
        ss += v[i] * v[i];
    }
#pragma unroll
    for (int off = 32; off > 0; off >>= 1) ss += __shfl_down(ss, off);
    __shared__ float wss[4];
    const int lane = t & 63, wv = t >> 6;
    if (lane == 0) wss[wv] = ss;
    __syncthreads();
    const float tot = wss[0] + wss[1] + wss[2] + wss[3];
    const float inv = 1.0f / fmaxf(sqrtf(tot), 1e-8f);
#pragma unroll
    for (int i = 0; i < 3; ++i)
        xn[(long)row * KD + t + 256 * i] = __float2bfloat16(v[i] * inv);
}

// ---------------- Kernel 2: 256x256-tile GEMM, 16 waves (4x4), fused Linear(1,2) ----
// OCCUPANCY EXPERIMENT vs R7: 1024 threads = 16 waves = 4 waves/SIMD (was 2).
// Per-wave output 64x64 (4x4 frags of 16x16), acc = 64 VGPR; per-ks operand
// slicing (a4[4], bn[2]) keeps regs under the 128-VGPR cap of launch_bounds(1024,4).
// K-loop sync structure identical to R7 (2-barrier K-tiles, depth-1-tile vmcnt).
__global__ __launch_bounds__(1024, 4) void sim_gemm16(
    const bf16_t* __restrict__ Xn,
    const float* __restrict__ fcw, const float* __restrict__ fcb,
    float* __restrict__ out)
{
    __shared__ __align__(16) bf16_t Ab[2][BM * 64];  // 2 x 32 KB
    __shared__ __align__(16) bf16_t Bb[2][BM * 64];  // 2 x 32 KB

    const int tid = threadIdx.x;
    const int wv  = tid >> 6;   // 0..15
    const int ln  = tid & 63;
    const int wm  = wv >> 2;    // 0..3 (M group, 64 rows)
    const int wn  = wv & 3;     // 0..3 (N group, 64 cols)

    // XCD-chunked decode (kept from R6; proven neutral, bijective)
    const int b  = blockIdx.x;
    const int x  = b & 7;
    const int s  = b >> 3;        // 0..31
    const int r  = s >> 4;        // sub-round 0/1
    const int sp = s & 15;
    const int bi = (x >> 1) * 4 + (sp & 3);            // 0..15
    const int bj = (x & 1) * 8 + r * 4 + (sp >> 2);    // 0..15
    const long Arow0 = (long)bi * BM, Brow0 = (long)bj * BM;

    // --- staging address precompute ---
    // 1024 threads x 16B = 16 KB per chunk; A/B tiles are 32 KB = 2 chunks.
    // Dest byte within 32KB tile: d = i*16384 + tid*16.
    // Source element = SWZ(d), SWZ(b) = b ^ (((b>>7)&7)<<4) (involution).
    int srow[2], scole[2];
#pragma unroll
    for (int i = 0; i < 2; ++i) {
        const int d = i * 16384 + tid * 16;
        const int sw = d ^ (((d >> 7) & 7) << 4);
        srow[i]  = sw >> 7;         // 0..255 within tile
        scole[i] = (sw & 127) >> 1; // element offset within 64-elem row
    }

#define ISSUE_CHUNK(isA, i_, tt) do {                                        \
        const long rb_ = ((isA) ? Arow0 : Brow0);                            \
        bf16_t* lb_ = ((isA) ? &Ab[(tt) & 1][0] : &Bb[(tt) & 1][0]);         \
        const bf16_t* g_ = Xn + (rb_ + srow[i_]) * (long)KD                  \
                           + (tt) * 64 + scole[i_];                          \
        bf16_t* l_ = lb_ + ((i_) * 16384 + (wv) * 1024) / 2;                 \
        GLOAD_LDS16(g_, l_);                                                 \
    } while (0)

#define ISSUE_TILE(tt) do {                                                  \
        ISSUE_CHUNK(1, 0, tt); ISSUE_CHUNK(1, 1, tt);                        \
        ISSUE_CHUNK(0, 0, tt); ISSUE_CHUNK(0, 1, tt);                        \
    } while (0)

    // --- ds_read addressing: element (row, k) at swizzled byte
    //     row*128 + ((ks*64 + (ln>>4)*16) ^ ((ln&7)<<4)) ---
    const int hi16 = (ln >> 4) << 4;
    const int swzm = (ln & 7) << 4;
    const int ke0 = ((0  + hi16) ^ swzm) >> 1;  // elem offset, ks=0
    const int ke1 = ((64 + hi16) ^ swzm) >> 1;  // elem offset, ks=1
    const int fr  = ln & 15;

    f32x4 acc[4][4] = {};
    bf16x8 a4[4], bn[2];

#define LDA_KS(KE) do {                                                      \
        _Pragma("unroll")                                                    \
        for (int mf = 0; mf < 4; ++mf)                                       \
            a4[mf] = *(const bf16x8*)&Ab[bb][(wm * 64 + mf * 16 + fr) * 64 + (KE)]; \
    } while (0)

#define LDB_KS(NH, KE) do {                                                  \
        _Pragma("unroll")                                                    \
        for (int nf = 0; nf < 2; ++nf)                                       \
            bn[nf] = *(const bf16x8*)&Bb[bb][(wn * 64 + (NH) * 32 + nf * 16 + fr) * 64 + (KE)]; \
    } while (0)

#define MMA_KS(NH) do {                                                      \
        __builtin_amdgcn_s_setprio(1);                                       \
        _Pragma("unroll")                                                    \
        for (int mf = 0; mf < 4; ++mf)                                       \
        _Pragma("unroll")                                                    \
        for (int nf = 0; nf < 2; ++nf)                                       \
            acc[mf][(NH)*2+nf] = __builtin_amdgcn_mfma_f32_16x16x32_bf16(    \
                a4[mf], bn[nf], acc[mf][(NH)*2+nf], 0, 0, 0);                \
        __builtin_amdgcn_s_setprio(0);                                       \
    } while (0)

    // --- prologue: stage tile0 + tile1; tile0 landed, tile1 in flight ---
    ISSUE_TILE(0);   // 4 loads
    ISSUE_TILE(1);   // 4 loads
    asm volatile("s_waitcnt vmcnt(4)" ::: "memory");
    FBAR();

    for (int t = 0; t < NT; ++t) {
        const int bb = t & 1;

        // K-tile body: two ks-slices, no internal barriers.
        LDA_KS(ke0); LDB_KS(0, ke0);
        MMA_KS(0);
        LDB_KS(1, ke0);
        MMA_KS(1);
        LDA_KS(ke1); LDB_KS(0, ke1);
        MMA_KS(0);
        LDB_KS(1, ke1);
        MMA_KS(1);

        if (t + 1 == NT) break;  // last tile: straight to epilogue

        FBAR();  // all waves' reads of bb complete (MFMA issue => operands waited)
        if (t + 2 < NT) {
            ISSUE_TILE(t + 2);   // 4 loads into bb (safe to overwrite)
            asm volatile("s_waitcnt vmcnt(4)" ::: "memory");  // t+1's 4 landed
        } else {
            asm volatile("s_waitcnt vmcnt(0)" ::: "memory");  // drain t+1
        }
        FBAR();  // all waves see next buffer staged
    }

    // --- epilogue: fused Linear(1,2), coalesced float2 stores ---
    const float w0 = fcw[0], w1 = fcw[1];
    const float c0 = fcb[0], c1 = fcb[1];
    const long row0 = Arow0 + wm * 64 + ((ln >> 4) << 2);
    const int  col0 = (int)Brow0 + wn * 64 + fr;
#pragma unroll
    for (int mi = 0; mi < 4; ++mi)
#pragma unroll
        for (int ni = 0; ni < 4; ++ni) {
            const int col = col0 + ni * 16;
#pragma unroll
            for (int rr = 0; rr < 4; ++rr) {
                const long row = row0 + mi * 16 + rr;
                const float sv = acc[mi][ni][rr];
                *(float2*)&out[(row * BDIM + col) * 2] =
                    make_float2(fmaf(sv, w0, c0), fmaf(sv, w1, c1));
            }
        }

#undef ISSUE_CHUNK
#undef ISSUE_TILE
#undef LDA_KS
#undef LDB_KS
#undef MMA_KS
}

extern "C" void kernel_launch(void* const* d_in, const int* in_sizes, int n_in,
                              void* d_out, int out_size, void* d_ws, size_t ws_size,
                              hipStream_t stream) {
    const float* x   = (const float*)d_in[0];
    const float* fcw = (const float*)d_in[1];
    const float* fcb = (const float*)d_in[2];
    float* out = (float*)d_out;

    __hip_bfloat16* xn = (__hip_bfloat16*)d_ws;  // 4096*768*2B = 6.3 MB

    normalize_rows<<<BDIM, 256, 0, stream>>>(x, xn);

    sim_gemm16<<<(BDIM / BM) * (BDIM / BM), 1024, 0, stream>>>(
        (const bf16_t*)xn, fcw, fcb, out);
}

// Round 9
// 52.228 us; speedup vs baseline: 1.1889x; 1.0096x over previous
//
#include <hip/hip_runtime.h>
#include <hip/hip_bf16.h>

typedef int i32x4 __attribute__((ext_vector_type(4)));
typedef int i32x8 __attribute__((ext_vector_type(8)));
typedef float f32x4 __attribute__((ext_vector_type(4)));

#define KD 768
#define BDIM 4096
#define NT 6         // K-tiles of BK=128
#define BM 256
#define E8M0_1_8TH 124   // 2^(124-127) = 1/8

#define GLOAD_LDS16(gptr, lptr)                                             \
    __builtin_amdgcn_global_load_lds(                                       \
        (const __attribute__((address_space(1))) unsigned int*)(gptr),      \
        (__attribute__((address_space(3))) unsigned int*)(lptr), 16, 0, 0)

// hw barrier + compiler memory fence, NO waitcnt drain (unlike __syncthreads)
#define FBAR() asm volatile("s_barrier" ::: "memory")

__device__ inline unsigned char f32_to_e4m3(float f) {
    // v_cvt_pk_fp8_f32 (OCP e4m3 on gfx950); take low byte
    int p = __builtin_amdgcn_cvt_pk_fp8_f32(f, f, 0, false);
    return (unsigned char)(p & 0xFF);
}

// ---------------- Kernel 1: row-normalize fp32 -> fp8 e4m3, pre-scaled x8 ----------------
// xn = 8 * x / max(||x||, eps). The x8 keeps elements (sigma~0.036) out of e4m3's
// subnormal range; compensated exactly by MX scales 2^-3 * 2^-3 in the MFMA.
__global__ __launch_bounds__(256) void normalize_rows_fp8(
    const float* __restrict__ x, unsigned char* __restrict__ xn)
{
    const int row = blockIdx.x;
    const int t = threadIdx.x;
    const float* xr = x + (long)row * KD;

    float v[3];
    float ss = 0.f;
#pragma unroll
    for (int i = 0; i < 3; ++i) {
        v[i] = xr[t + 256 * i];
        ss += v[i] * v[i];
    }
#pragma unroll
    for (int off = 32; off > 0; off >>= 1) ss += __shfl_down(ss, off);
    __shared__ float wss[4];
    const int lane = t & 63, wv = t >> 6;
    if (lane == 0) wss[wv] = ss;
    __syncthreads();
    const float tot = wss[0] + wss[1] + wss[2] + wss[3];
    const float inv = 8.0f / fmaxf(sqrtf(tot), 1e-8f);
#pragma unroll
    for (int i = 0; i < 3; ++i)
        xn[(long)row * KD + t + 256 * i] = f32_to_e4m3(v[i] * inv);
}

// ---------------- Kernel 2: 256x256-tile MX-fp8 GEMM (K=128/instr), fused Linear(1,2) ----
// R8 skeleton (16 waves 4x4, 2-barrier K-tiles, depth-1-tile vmcnt) with:
//   - fp8 e4m3 operands, mfma_scale_f32_16x16x128_f8f6f4, scales 2^-3 per side
//   - BK=128 -> 6 K-tiles; LDS 2x(32+32) KB = 128 KB
//   - per K-tile per wave: 8 A + 8 B ds_read_b128 (half the bytes of bf16), 16 MFMA
__global__ __launch_bounds__(1024, 4) void sim_gemm_mx(
    const unsigned char* __restrict__ Xn,
    const float* __restrict__ fcw, const float* __restrict__ fcb,
    float* __restrict__ out)
{
    __shared__ __align__(16) unsigned char Ab[2][BM * 128];  // 2 x 32 KB
    __shared__ __align__(16) unsigned char Bb[2][BM * 128];  // 2 x 32 KB

    const int tid = threadIdx.x;
    const int wv  = tid >> 6;   // 0..15
    const int ln  = tid & 63;
    const int wm  = wv >> 2;    // 0..3 (M group, 64 rows)
    const int wn  = wv & 3;     // 0..3 (N group, 64 cols)

    // XCD-chunked decode (neutral, bijective — kept)
    const int b  = blockIdx.x;
    const int x  = b & 7;
    const int s  = b >> 3;
    const int r  = s >> 4;
    const int sp = s & 15;
    const int bi = (x >> 1) * 4 + (sp & 3);
    const int bj = (x & 1) * 8 + r * 4 + (sp >> 2);
    const long Arow0 = (long)bi * BM, Brow0 = (long)bj * BM;

    // --- staging precompute: tile = 32 KB = 2 chunks of 16 KB (1024 thr x 16 B).
    // Dest byte d = i*16384 + tid*16; source = SWZ(d), SWZ(b) = b ^ (((b>>7)&7)<<4).
    int srow[2], scolB[2];
#pragma unroll
    for (int i = 0; i < 2; ++i) {
        const int d = i * 16384 + tid * 16;
        const int sw = d ^ (((d >> 7) & 7) << 4);
        srow[i]  = sw >> 7;     // 0..255 row within tile
        scolB[i] = sw & 127;    // byte (= element) offset within 128-B row
    }

#define ISSUE_CHUNK(isA, i_, tt) do {                                        \
        const long rb_ = ((isA) ? Arow0 : Brow0);                            \
        unsigned char* lb_ = ((isA) ? &Ab[(tt) & 1][0] : &Bb[(tt) & 1][0]);  \
        const unsigned char* g_ = Xn + (rb_ + srow[i_]) * (long)KD           \
                                  + (tt) * 128 + scolB[i_];                  \
        unsigned char* l_ = lb_ + (i_) * 16384 + (wv) * 1024;                \
        GLOAD_LDS16(g_, l_);                                                 \
    } while (0)

#define ISSUE_TILE(tt) do {                                                  \
        ISSUE_CHUNK(1, 0, tt); ISSUE_CHUNK(1, 1, tt);                        \
        ISSUE_CHUNK(0, 0, tt); ISSUE_CHUNK(0, 1, tt);                        \
    } while (0)

    // --- ds_read addressing: frag row = base + (ln&15); lane k-block q = ln>>4
    //     byte = row*128 + (kb ^ ((row&7)<<4)), kb in {q*32, q*32+16}
    const int fr  = ln & 15;
    const int q32 = (ln >> 4) << 5;
    const int swz = (ln & 7) << 4;
    const int kb0 = (q32)      ^ swz;
    const int kb1 = (q32 + 16) ^ swz;

    f32x4 acc[4][4] = {};
    i32x8 av[4];

#define LDA_ALL() do {                                                       \
        _Pragma("unroll")                                                    \
        for (int mf = 0; mf < 4; ++mf) {                                     \
            const int r_ = (wm * 64 + mf * 16 + fr) * 128;                   \
            i32x4 lo = *(const i32x4*)&Ab[bb][r_ + kb0];                     \
            i32x4 hi = *(const i32x4*)&Ab[bb][r_ + kb1];                     \
            av[mf] = __builtin_shufflevector(lo, hi, 0, 1, 2, 3, 4, 5, 6, 7);\
        }                                                                    \
    } while (0)

#define DO_NF(nf) do {                                                       \
        const int r_ = (wn * 64 + (nf) * 16 + fr) * 128;                     \
        i32x4 lo = *(const i32x4*)&Bb[bb][r_ + kb0];                         \
        i32x4 hi = *(const i32x4*)&Bb[bb][r_ + kb1];                         \
        i32x8 bv = __builtin_shufflevector(lo, hi, 0, 1, 2, 3, 4, 5, 6, 7);  \
        __builtin_amdgcn_s_setprio(1);                                       \
        _Pragma("unroll")                                                    \
        for (int mf = 0; mf < 4; ++mf)                                       \
            acc[mf][nf] = __builtin_amdgcn_mfma_scale_f32_16x16x128_f8f6f4(  \
                av[mf], bv, acc[mf][nf], 0, 0,                               \
                0, E8M0_1_8TH, 0, E8M0_1_8TH);                               \
        __builtin_amdgcn_s_setprio(0);                                       \
    } while (0)

    // --- prologue: stage tile0 + tile1; tile0 landed, tile1 in flight ---
    ISSUE_TILE(0);   // 4 loads
    ISSUE_TILE(1);   // 4 loads
    asm volatile("s_waitcnt vmcnt(4)" ::: "memory");
    FBAR();

    for (int t = 0; t < NT; ++t) {
        const int bb = t & 1;

        LDA_ALL();
        DO_NF(0); DO_NF(1); DO_NF(2); DO_NF(3);

        if (t + 1 == NT) break;

        FBAR();  // all waves done reading bb (MFMA issue => operand waits satisfied)
        if (t + 2 < NT) {
            ISSUE_TILE(t + 2);   // into bb, safe to overwrite
            asm volatile("s_waitcnt vmcnt(4)" ::: "memory");  // t+1's 4 landed
        } else {
            asm volatile("s_waitcnt vmcnt(0)" ::: "memory");
        }
        FBAR();
    }

    // --- epilogue: fused Linear(1,2), coalesced float2 stores ---
    const float w0 = fcw[0], w1 = fcw[1];
    const float c0 = fcb[0], c1 = fcb[1];
    const long row0 = Arow0 + wm * 64 + ((ln >> 4) << 2);
    const int  col0 = (int)Brow0 + wn * 64 + fr;
#pragma unroll
    for (int mi = 0; mi < 4; ++mi)
#pragma unroll
        for (int ni = 0; ni < 4; ++ni) {
            const int col = col0 + ni * 16;
#pragma unroll
            for (int rr = 0; rr < 4; ++rr) {
                const long row = row0 + mi * 16 + rr;
                const float sv = acc[mi][ni][rr];
                *(float2*)&out[(row * BDIM + col) * 2] =
                    make_float2(fmaf(sv, w0, c0), fmaf(sv, w1, c1));
            }
        }

#undef ISSUE_CHUNK
#undef ISSUE_TILE
#undef LDA_ALL
#undef DO_NF
}

extern "C" void kernel_launch(void* const* d_in, const int* in_sizes, int n_in,
                              void* d_out, int out_size, void* d_ws, size_t ws_size,
                              hipStream_t stream) {
    const float* x   = (const float*)d_in[0];
    const float* fcw = (const float*)d_in[1];
    const float* fcb = (const float*)d_in[2];
    float* out = (float*)d_out;

    unsigned char* xn = (unsigned char*)d_ws;  // 4096*768*1B = 3.1 MB

    normalize_rows_fp8<<<BDIM, 256, 0, stream>>>(x, xn);

    sim_gemm_mx<<<(BDIM / BM) * (BDIM / BM), 1024, 0, stream>>>(
        xn, fcw, fcb, out);
}

// Round 10
// 41.334 us; speedup vs baseline: 1.5022x; 1.2636x over previous
//
#include <hip/hip_runtime.h>
#include <hip/hip_bf16.h>

typedef int i32x4 __attribute__((ext_vector_type(4)));
typedef int i32x8 __attribute__((ext_vector_type(8)));
typedef float f32x4 __attribute__((ext_vector_type(4)));

#define KD 768
#define BDIM 4096
#define NSTRIP 16        // 512 cols / 32
#define E8M0_1_8TH 124   // 2^(124-127) = 1/8
#define BLDS 24576       // 32 cols x 768 K bytes

#define GLOAD_LDS16(gptr, lptr)                                             \
    __builtin_amdgcn_global_load_lds(                                       \
        (const __attribute__((address_space(1))) unsigned int*)(gptr),      \
        (__attribute__((address_space(3))) unsigned int*)(lptr), 16, 0, 0)

#define FBAR() asm volatile("s_barrier" ::: "memory")
#define SCHED_FENCE() __builtin_amdgcn_sched_barrier(0)

__device__ inline unsigned char f32_to_e4m3(float f) {
    int p = __builtin_amdgcn_cvt_pk_fp8_f32(f, f, 0, false);
    return (unsigned char)(p & 0xFF);
}

// ---------------- Kernel 1: row-normalize fp32 -> fp8 e4m3, pre-scaled x8 ----------------
// xn = 8 * x / max(||x||, eps); the x8 dodges e4m3's subnormal floor, compensated
// exactly by MX scales 2^-3 * 2^-3 in the MFMA.
__global__ __launch_bounds__(256) void normalize_rows_fp8(
    const float* __restrict__ x, unsigned char* __restrict__ xn)
{
    const int row = blockIdx.x;
    const int t = threadIdx.x;
    const float* xr = x + (long)row * KD;

    float v[3];
    float ss = 0.f;
#pragma unroll
    for (int i = 0; i < 3; ++i) {
        v[i] = xr[t + 256 * i];
        ss += v[i] * v[i];
    }
#pragma unroll
    for (int off = 32; off > 0; off >>= 1) ss += __shfl_down(ss, off);
    __shared__ float wss[4];
    const int lane = t & 63, wv = t >> 6;
    if (lane == 0) wss[wv] = ss;
    __syncthreads();
    const float tot = wss[0] + wss[1] + wss[2] + wss[3];
    const float inv = 8.0f / fmaxf(sqrtf(tot), 1e-8f);
#pragma unroll
    for (int i = 0; i < 3; ++i)
        xn[(long)row * KD + t + 256 * i] = f32_to_e4m3(v[i] * inv);
}

// ---------------- Kernel 2: A-reg-resident, B/write-STREAMING MX-fp8 GEMM ----------------
// Block = 128 rows x 512 cols. A (128 x 768 fp8) in registers (96 VGPR/lane, loaded once).
// B streams in 16 strips of 32 cols via LDS dbuf (2 x 24.6 KB); each strip's 32 KB of
// output stores immediately -> writes stream for the whole kernel, no end drain.
// 8 waves (4M x 2N): wave = 32 rows x 16 cols per strip; per strip: 12 ds_read_b128,
// 12 MFMA(K=128), 8 float2 stores.
// B LDS layout [kk][o][col32][q4][16B]: a wave's 64 lanes read contiguous 1024 B
// -> conflict-free. Staging dest chunk (16B) maps to contiguous 16B of Xn row 'col'.
__global__ __launch_bounds__(512) void sim_gemm_stream(
    const unsigned char* __restrict__ Xn,
    const float* __restrict__ fcw, const float* __restrict__ fcb,
    float* __restrict__ out)
{
    __shared__ __align__(16) unsigned char Bb[2][BLDS];  // 2 x 24 KB

    const int tid = threadIdx.x;
    const int wv  = tid >> 6;    // 0..7
    const int ln  = tid & 63;
    const int wm  = wv >> 1;     // 0..3 (M group, 32 rows)
    const int wn  = wv & 1;      // 0..1 (N group, 16 cols)
    const int fr  = ln & 15;
    const int q   = ln >> 4;     // 0..3

    const int jc = blockIdx.x;   // 0..7   col chunk (512 cols)
    const int bi = blockIdx.y;   // 0..31  row chunk (128 rows)
    const long Arow0 = (long)bi * 128;
    const long Bcol0 = (long)jc * 512;

    // --- B staging precompute: dest byte d = i*8192 + tid*16, i<3.
    //     d -> kk=d>>12, o=(d>>11)&1, col=(d>>6)&31, q=(d>>4)&3
    //     source: Xn row (Bcol0+s*32+col), k byte = kk*128+q*32+o*16 (16B contiguous)
    int scol[3], skoff[3];
#pragma unroll
    for (int i = 0; i < 3; ++i) {
        const int d = i * 8192 + tid * 16;
        scol[i]  = (d >> 6) & 31;
        skoff[i] = ((d >> 12) << 7) + (((d >> 4) & 3) << 5) + (((d >> 11) & 1) << 4);
    }

#define ISSUE_B(s) do {                                                      \
        _Pragma("unroll")                                                    \
        for (int i_ = 0; i_ < 3; ++i_) {                                     \
            const unsigned char* g_ = Xn                                     \
                + (Bcol0 + (s) * 32 + scol[i_]) * (long)KD + skoff[i_];      \
            unsigned char* l_ = &Bb[(s) & 1][0] + i_ * 8192 + wv * 1024;     \
            GLOAD_LDS16(g_, l_);                                             \
        }                                                                    \
    } while (0)

    // --- A fragments: global -> registers, once. 2 M-frags x 6 kk x 32 B = 96 VGPR.
    i32x8 aF[2][6];
    {
        const unsigned char* pa0 = Xn + (Arow0 + wm * 32 + fr) * (long)KD + q * 32;
        const unsigned char* pa1 = pa0 + 16 * (long)KD;
#pragma unroll
        for (int kk = 0; kk < 6; ++kk) {
            i32x4 lo0 = *(const i32x4*)(pa0 + kk * 128);
            i32x4 hi0 = *(const i32x4*)(pa0 + kk * 128 + 16);
            aF[0][kk] = __builtin_shufflevector(lo0, hi0, 0, 1, 2, 3, 4, 5, 6, 7);
            i32x4 lo1 = *(const i32x4*)(pa1 + kk * 128);
            i32x4 hi1 = *(const i32x4*)(pa1 + kk * 128 + 16);
            aF[1][kk] = __builtin_shufflevector(lo1, hi1, 0, 1, 2, 3, 4, 5, 6, 7);
        }
    }

    const float w0 = fcw[0], w1 = fcw[1];
    const float c0 = fcb[0], c1 = fcb[1];

    // --- prologue: stage strip 0; drain everything once; sync ---
    ISSUE_B(0);
    asm volatile("s_waitcnt vmcnt(0)" ::: "memory");
    FBAR();

    const int colbase = (int)Bcol0 + wn * 16 + fr;
    const long rowb   = Arow0 + wm * 32 + q * 4;

    for (int s = 0; s < NSTRIP; ++s) {
        const int bb = s & 1;

        if (s + 1 < NSTRIP) ISSUE_B(s + 1);
        SCHED_FENCE();  // pin emitted order: [3 staging loads] before strip's stores

        // compute strip: 6 kk slices, acc fresh per strip
        f32x4 acc[2] = {};
#pragma unroll
        for (int kk = 0; kk < 6; ++kk) {
            const int bo = kk * 4096 + (wn * 16 + fr) * 64 + q * 16;
            i32x4 lo = *(const i32x4*)&Bb[bb][bo];
            i32x4 hi = *(const i32x4*)&Bb[bb][bo + 2048];
            i32x8 bv = __builtin_shufflevector(lo, hi, 0, 1, 2, 3, 4, 5, 6, 7);
            __builtin_amdgcn_s_setprio(1);
            acc[0] = __builtin_amdgcn_mfma_scale_f32_16x16x128_f8f6f4(
                aF[0][kk], bv, acc[0], 0, 0, 0, E8M0_1_8TH, 0, E8M0_1_8TH);
            acc[1] = __builtin_amdgcn_mfma_scale_f32_16x16x128_f8f6f4(
                aF[1][kk], bv, acc[1], 0, 0, 0, E8M0_1_8TH, 0, E8M0_1_8TH);
            __builtin_amdgcn_s_setprio(0);
        }

        // stream this strip's output: 8 float2 stores/lane
        const int col = colbase + s * 32;
#pragma unroll
        for (int mf = 0; mf < 2; ++mf)
#pragma unroll
            for (int rr = 0; rr < 4; ++rr) {
                const long row = rowb + mf * 16 + rr;
                const float sv = acc[mf][rr];
                *(float2*)&out[(row * BDIM + col) * 2] =
                    make_float2(fmaf(sv, w0, c0), fmaf(sv, w1, c1));
            }

        if (s + 1 < NSTRIP) {
            // in-order vmcnt: history [.. st(s-1) x8][B(s+1) x3][st(s) x8]
            // count<=8 => B(s+1) landed; does NOT drain this strip's stores.
            asm volatile("s_waitcnt vmcnt(8)" ::: "memory");
            FBAR();  // next buffer visible to all waves; prior buffer reads done
        }
    }

#undef ISSUE_B
}

extern "C" void kernel_launch(void* const* d_in, const int* in_sizes, int n_in,
                              void* d_out, int out_size, void* d_ws, size_t ws_size,
                              hipStream_t stream) {
    const float* x   = (const float*)d_in[0];
    const float* fcw = (const float*)d_in[1];
    const float* fcb = (const float*)d_in[2];
    float* out = (float*)d_out;

    unsigned char* xn = (unsigned char*)d_ws;  // 4096*768*1B = 3.1 MB

    normalize_rows_fp8<<<BDIM, 256, 0, stream>>>(x, xn);

    dim3 grid(8, 32);  // jc x bi = 256 blocks, 1/CU
    sim_gemm_stream<<<grid, 512, 0, stream>>>(xn, fcw, fcb, out);
}

// Round 11
// 40.387 us; speedup vs baseline: 1.5374x; 1.0234x over previous
//
#include <hip/hip_runtime.h>
#include <hip/hip_bf16.h>

typedef int i32x4 __attribute__((ext_vector_type(4)));
typedef int i32x8 __attribute__((ext_vector_type(8)));
typedef float f32x4 __attribute__((ext_vector_type(4)));

#define KD 768
#define BDIM 4096
#define NSTRIP 16        // 512 cols / 32
#define E8M0_1_8TH 124   // 2^(124-127) = 1/8
#define BLDS 24576       // 32 cols x 768 K bytes

#define GLOAD_LDS16(gptr, lptr)                                             \
    __builtin_amdgcn_global_load_lds(                                       \
        (const __attribute__((address_space(1))) unsigned int*)(gptr),      \
        (__attribute__((address_space(3))) unsigned int*)(lptr), 16, 0, 0)

#define FBAR() asm volatile("s_barrier" ::: "memory")
#define SCHED_FENCE() __builtin_amdgcn_sched_barrier(0)

__device__ inline unsigned char f32_to_e4m3(float f) {
    int p = __builtin_amdgcn_cvt_pk_fp8_f32(f, f, 0, false);
    return (unsigned char)(p & 0xFF);
}

// ---------------- Kernel 1: row-normalize fp32 -> fp8 e4m3, pre-scaled x8 ----------------
__global__ __launch_bounds__(256) void normalize_rows_fp8(
    const float* __restrict__ x, unsigned char* __restrict__ xn)
{
    const int row = blockIdx.x;
    const int t = threadIdx.x;
    const float* xr = x + (long)row * KD;

    float v[3];
    float ss = 0.f;
#pragma unroll
    for (int i = 0; i < 3; ++i) {
        v[i] = xr[t + 256 * i];
        ss += v[i] * v[i];
    }
#pragma unroll
    for (int off = 32; off > 0; off >>= 1) ss += __shfl_down(ss, off);
    __shared__ float wss[4];
    const int lane = t & 63, wv = t >> 6;
    if (lane == 0) wss[wv] = ss;
    __syncthreads();
    const float tot = wss[0] + wss[1] + wss[2] + wss[3];
    const float inv = 8.0f / fmaxf(sqrtf(tot), 1e-8f);
#pragma unroll
    for (int i = 0; i < 3; ++i)
        xn[(long)row * KD + t + 256 * i] = f32_to_e4m3(v[i] * inv);
}

// ---------------- Kernel 2: streaming MX-fp8 GEMM, 2 blocks/CU ----------------
// OCCUPANCY CHANGE vs R10: block = 64 rows x 512 cols (was 128), grid 512 = 2/CU,
// LDS 48 KB/block, A-regs 48 VGPR, launch_bounds(512,4) -> 16 waves/CU = 4/SIMD.
// Two co-resident pipelines hide each other's per-strip barrier/latency bubbles.
// Everything else (strip structure, B layout, vmcnt discipline, store pattern,
// quantization, accumulation order) identical to R10.
// 8 waves (4M x 2N): wave = 16 rows x 16 cols per strip; per strip per wave:
// 12 ds_read_b128, 6 MFMA(K=128), 4 float2 stores.
__global__ __launch_bounds__(512, 4) void sim_gemm_stream(
    const unsigned char* __restrict__ Xn,
    const float* __restrict__ fcw, const float* __restrict__ fcb,
    float* __restrict__ out)
{
    __shared__ __align__(16) unsigned char Bb[2][BLDS];  // 2 x 24 KB

    const int tid = threadIdx.x;
    const int wv  = tid >> 6;    // 0..7
    const int ln  = tid & 63;
    const int wm  = wv >> 1;     // 0..3 (M group, 16 rows)
    const int wn  = wv & 1;      // 0..1 (N group, 16 cols)
    const int fr  = ln & 15;
    const int q   = ln >> 4;     // 0..3

    const int jc = blockIdx.x;   // 0..7   col chunk (512 cols)
    const int bi = blockIdx.y;   // 0..63  row chunk (64 rows)
    const long Arow0 = (long)bi * 64;
    const long Bcol0 = (long)jc * 512;

    // --- B staging precompute: dest byte d = i*8192 + tid*16, i<3.
    //     d -> kk=d>>12, o=(d>>11)&1, col=(d>>6)&31, q=(d>>4)&3
    //     source: Xn row (Bcol0+s*32+col), k byte = kk*128+q*32+o*16 (16B contiguous)
    int scol[3], skoff[3];
#pragma unroll
    for (int i = 0; i < 3; ++i) {
        const int d = i * 8192 + tid * 16;
        scol[i]  = (d >> 6) & 31;
        skoff[i] = ((d >> 12) << 7) + (((d >> 4) & 3) << 5) + (((d >> 11) & 1) << 4);
    }

#define ISSUE_B(s) do {                                                      \
        _Pragma("unroll")                                                    \
        for (int i_ = 0; i_ < 3; ++i_) {                                     \
            const unsigned char* g_ = Xn                                     \
                + (Bcol0 + (s) * 32 + scol[i_]) * (long)KD + skoff[i_];      \
            unsigned char* l_ = &Bb[(s) & 1][0] + i_ * 8192 + wv * 1024;     \
            GLOAD_LDS16(g_, l_);                                             \
        }                                                                    \
    } while (0)

    // --- A fragments: global -> registers, once. 1 M-frag x 6 kk x 32 B = 48 VGPR.
    i32x8 aF[6];
    {
        const unsigned char* pa = Xn + (Arow0 + wm * 16 + fr) * (long)KD + q * 32;
#pragma unroll
        for (int kk = 0; kk < 6; ++kk) {
            i32x4 lo = *(const i32x4*)(pa + kk * 128);
            i32x4 hi = *(const i32x4*)(pa + kk * 128 + 16);
            aF[kk] = __builtin_shufflevector(lo, hi, 0, 1, 2, 3, 4, 5, 6, 7);
        }
    }

    const float w0 = fcw[0], w1 = fcw[1];
    const float c0 = fcb[0], c1 = fcb[1];

    // --- prologue: stage strip 0; drain once; sync ---
    ISSUE_B(0);
    asm volatile("s_waitcnt vmcnt(0)" ::: "memory");
    FBAR();

    const int colbase = (int)Bcol0 + wn * 16 + fr;
    const long rowb   = Arow0 + wm * 16 + q * 4;

    for (int s = 0; s < NSTRIP; ++s) {
        const int bb = s & 1;

        if (s + 1 < NSTRIP) ISSUE_B(s + 1);
        SCHED_FENCE();  // pin order: [3 staging loads] before this strip's stores

        // compute strip: 6 kk slices, acc fresh per strip
        f32x4 acc = {};
#pragma unroll
        for (int kk = 0; kk < 6; ++kk) {
            const int bo = kk * 4096 + (wn * 16 + fr) * 64 + q * 16;
            i32x4 lo = *(const i32x4*)&Bb[bb][bo];
            i32x4 hi = *(const i32x4*)&Bb[bb][bo + 2048];
            i32x8 bv = __builtin_shufflevector(lo, hi, 0, 1, 2, 3, 4, 5, 6, 7);
            __builtin_amdgcn_s_setprio(1);
            acc = __builtin_amdgcn_mfma_scale_f32_16x16x128_f8f6f4(
                aF[kk], bv, acc, 0, 0, 0, E8M0_1_8TH, 0, E8M0_1_8TH);
            __builtin_amdgcn_s_setprio(0);
        }

        // stream this strip's output: 4 float2 stores/lane
        const int col = colbase + s * 32;
#pragma unroll
        for (int rr = 0; rr < 4; ++rr) {
            const long row = rowb + rr;
            const float sv = acc[rr];
            *(float2*)&out[(row * BDIM + col) * 2] =
                make_float2(fmaf(sv, w0, c0), fmaf(sv, w1, c1));
        }

        if (s + 1 < NSTRIP) {
            // in-order vmcnt: the 4 youngest ops are this strip's stores;
            // <=4 outstanding => B(s+1)'s 3 loads (older) have landed.
            asm volatile("s_waitcnt vmcnt(4)" ::: "memory");
            FBAR();  // next buffer visible; prior buffer reads complete
        }
    }

#undef ISSUE_B
}

extern "C" void kernel_launch(void* const* d_in, const int* in_sizes, int n_in,
                              void* d_out, int out_size, void* d_ws, size_t ws_size,
                              hipStream_t stream) {
    const float* x   = (const float*)d_in[0];
    const float* fcw = (const float*)d_in[1];
    const float* fcb = (const float*)d_in[2];
    float* out = (float*)d_out;

    unsigned char* xn = (unsigned char*)d_ws;  // 4096*768*1B = 3.1 MB

    normalize_rows_fp8<<<BDIM, 256, 0, stream>>>(x, xn);

    dim3 grid(8, 64);  // jc x bi = 512 blocks, 2/CU
    sim_gemm_stream<<<grid, 512, 0, stream>>>(xn, fcw, fcb, out);
}